// Round 4
// baseline (105.642 us; speedup 1.0000x reference)
//
#include <hip/hip_runtime.h>
#include <math.h>

#define H_  128
#define N_  64
#define L_  4096
#define B_  8
#define LC  128
#define NCH 32     // L_/LC

typedef _Float16 f16;
typedef _Float16 half8 __attribute__((ext_vector_type(8)));
typedef _Float16 f16x4 __attribute__((ext_vector_type(4)));
typedef _Float16 f16x2 __attribute__((ext_vector_type(2)));
typedef float    floatx4 __attribute__((ext_vector_type(4)));

// ws layout (bytes): T | G | M (each H_*LC*LC f16) | q (H_*N_*2 f32)
#define WS_T 0
#define WS_G ((size_t)H_*LC*LC*2)
#define WS_M ((size_t)2*H_*LC*LC*2)
#define WS_Q ((size_t)3*H_*LC*LC*2)

// per-(h,n) scalar constants; double only for the one-time closed forms
__device__ __forceinline__ void dss_consts(int h, int n,
    const float* __restrict__ Lre, const float* __restrict__ Lim,
    const float* __restrict__ Wri, const float* __restrict__ lstep,
    float& af, float& bf, float& crf, float& cif, float& qrf, float& qif)
{
    const float stepf = expf(lstep[h]);
    const float a  = stepf * Lre[h*N_ + n];     // f32, matches reference P build
    const float bp = stepf * Lim[h*N_ + n];
    const double ad = (double)a, bd = (double)bp;
    const double em = exp(ad);
    const double rre = em * cos(bd), rim = em * sin(bd);
    const double eL = exp(ad * (double)L_);
    const double rLre = eL * cos(bd * (double)L_), rLim = eL * sin(bd * (double)L_);
    const double nre = 1.0 - rLre, nim = -rLim;       // s = (1 - r^L)/(1 - r)
    const double dre = 1.0 - rre,  dim = -rim;
    const double dm  = dre*dre + dim*dim;
    const double sre = (nre*dre + nim*dim) / dm;
    const double sim = (nim*dre - nre*dim) / dm;
    const double wre = (double)Wri[(h*N_ + n)*2 + 0];
    const double wim = (double)Wri[(h*N_ + n)*2 + 1];
    const double lre = (double)Lre[h*N_ + n], lim = (double)Lim[h*N_ + n];
    const double lm  = lre*lre + lim*lim;
    const double wor = (wre*lre + wim*lim) / lm;      // W / Lambda
    const double woi = (wim*lre - wre*lim) / lm;
    const double sm  = sre*sre + sim*sim + 1e-7;      // c = (W/L)*conj(s)/(|s|^2+eps)
    const double eC  = exp(ad * (double)LC);
    af = a; bf = bp;
    crf = (float)((wor*sre + woi*sim) / sm);
    cif = (float)((woi*sre - wor*sim) / sm);
    qrf = (float)(eC * cos(bd * (double)LC));
    qif = (float)(eC * sin(bd * (double)LC));
}

// ---------------- K1: build T/G/M/q, one block per (h, matrix) ----------------
// T[i*128+j] = (i>=j) ? K'[i-j] : 0      (K'[0] = K[0]+D)
// G[(2m)*128+k]   = Re(r_m^{127-k}),  G[(2m+1)*128+k] = Im(r_m^{127-k})
// M[j*128+2m]     = 16*Re(c_m r_m^{j+1}), M[j*128+2m+1] = -16*Im(c_m r_m^{j+1})
__global__ __launch_bounds__(256)
void dss_prep(const float* __restrict__ Lre, const float* __restrict__ Lim,
              const float* __restrict__ Wri, const float* __restrict__ Dv,
              const float* __restrict__ lstep, char* __restrict__ ws)
{
    __shared__ float s_a[N_], s_b[N_], s_cr[N_], s_ci[N_];
    __shared__ float sKp[2][128];
    __shared__ float sK[128];
    const int h = blockIdx.x;
    const int which = blockIdx.y;
    const int t = threadIdx.x;

    if (t < N_) {
        float a, b, cr, ci, qr, qi;
        dss_consts(h, t, Lre, Lim, Wri, lstep, a, b, cr, ci, qr, qi);
        s_a[t] = a; s_b[t] = b; s_cr[t] = cr; s_ci[t] = ci;
        if (which == 0) {
            float* qg = (float*)(ws + WS_Q) + (size_t)h*N_*2;
            qg[2*t] = qr; qg[2*t+1] = qi;
        }
    }
    __syncthreads();

    if (which == 0) {          // ---- T (local causal Toeplitz of K) ----
        const int tt = t & 127, hf = t >> 7;   // 128 lags x 2 mode-halves
        float acc = 0.f;
        #pragma unroll
        for (int m = 0; m < 32; ++m) {
            const int n = hf*32 + m;
            const float ex = expf(s_a[n] * (float)tt);
            float sn, cs; sincosf(s_b[n] * (float)tt, &sn, &cs);
            acc = fmaf(ex, s_cr[n]*cs - s_ci[n]*sn, acc);   // Re(c r^tt)
        }
        sKp[hf][tt] = acc;
        __syncthreads();
        if (t < 128) {
            float kv = sKp[0][t] + sKp[1][t];
            if (t == 0) kv += Dv[h];           // fold D*u into diagonal
            sK[t] = kv;
        }
        __syncthreads();
        f16* Tg = (f16*)(ws + WS_T) + (size_t)h*LC*LC;
        #pragma unroll
        for (int i = 0; i < 8; ++i) {
            const int e8 = t + i*256;
            const int row = e8 >> 4, c0 = (e8 & 15) * 8;
            half8 pv;
            #pragma unroll
            for (int j = 0; j < 8; ++j) {
                const int col = c0 + j;
                pv[j] = (f16)((row >= col) ? sK[row - col] : 0.f);
            }
            *reinterpret_cast<half8*>(&Tg[row*LC + c0]) = pv;
        }
    } else if (which == 1) {   // ---- G (end-state gather) ----
        f16* Gg = (f16*)(ws + WS_G) + (size_t)h*LC*LC;
        #pragma unroll
        for (int i = 0; i < 8; ++i) {
            const int e8 = t + i*256;
            const int row = e8 >> 4, c0 = (e8 & 15) * 8;
            const int m = row >> 1, im = row & 1;
            const float a = s_a[m], b = s_b[m];
            half8 pv;
            #pragma unroll
            for (int j = 0; j < 8; ++j) {
                const float p = (float)(127 - (c0 + j));
                const float ex = expf(a * p);
                float sn, cs; sincosf(b * p, &sn, &cs);
                pv[j] = (f16)(im ? ex*sn : ex*cs);
            }
            *reinterpret_cast<half8*>(&Gg[row*LC + c0]) = pv;
        }
    } else {                   // ---- M (carry broadcast, x16 scale) ----
        f16* Mg = (f16*)(ws + WS_M) + (size_t)h*LC*LC;
        #pragma unroll
        for (int i = 0; i < 8; ++i) {
            const int e8 = t + i*256;
            const int row = e8 >> 4, c0 = (e8 & 15) * 8;   // 4 modes per slot
            const float p = (float)(row + 1);
            half8 pv;
            #pragma unroll
            for (int mm = 0; mm < 4; ++mm) {
                const int m = (c0 >> 1) + mm;
                const float ex = expf(s_a[m] * p);
                float sn, cs; sincosf(s_b[m] * p, &sn, &cs);
                const float pr = ex*cs, pi = ex*sn;
                pv[2*mm]   = (f16)( 16.f * (s_cr[m]*pr - s_ci[m]*pi));  //  16*Re
                pv[2*mm+1] = (f16)(-16.f * (s_cr[m]*pi + s_ci[m]*pr));  // -16*Im
            }
            *reinterpret_cast<half8*>(&Mg[row*LC + c0]) = pv;
        }
    }
}

// ---------------- K2: main — 3 batched GEMMs + carry scan ----------------
__global__ __launch_bounds__(256, 4)
void dss_main(const float* __restrict__ u, const char* __restrict__ ws,
              float* __restrict__ out)
{
    __shared__ f16   sU[NCH][132];    // u chunks, f16, padded rows (8.25 KB)
    __shared__ float sE[NCH][132];    // end-states f32, later y (16.5 KB)
    __shared__ f16   sC[NCH][132];    // carries (f16, scaled 1/16)

    const int t  = threadIdx.x;
    const int bh = blockIdx.x;
    const int h  = bh & (H_-1);
    const f16* Tg = (const f16*)(ws + WS_T) + (size_t)h*LC*LC;
    const f16* Gg = (const f16*)(ws + WS_G) + (size_t)h*LC*LC;
    const f16* Mg = (const f16*)(ws + WS_M) + (size_t)h*LC*LC;
    const float* qg = (const float*)(ws + WS_Q) + (size_t)h*N_*2;

    // stage u -> f16 LDS
    {
        const float4* up = reinterpret_cast<const float4*>(u + (size_t)bh * L_);
        #pragma unroll
        for (int i = 0; i < L_/4/256; ++i) {
            const int e4 = t + i*256;
            const float4 v = up[e4];
            const int row = e4 >> 5, c4 = (e4 & 31) * 4;
            f16x4 pv = { (f16)v.x, (f16)v.y, (f16)v.z, (f16)v.w };
            *reinterpret_cast<f16x4*>(&sU[row][c4]) = pv;
        }
    }
    __syncthreads();

    const int w  = t >> 6;     // wave 0..3 -> n-tiles {2w, 2w+1}
    const int l  = t & 63;
    const int lr = l & 15;     // tile row/col index
    const int lg = l >> 4;     // k-group / output-row group

    floatx4 accA[2][2] = {};   // [mtile][nt] — y accumulators (phases A + C)
    floatx4 accB[2][2] = {};   // end-state accumulators (phase B)

    // phases A (Y_loc = U*T) and B (E = U*G), fused over the K loop
    #pragma unroll
    for (int ks = 0; ks < 4; ++ks) {
        const int ko = ks*32 + lg*8;
        const half8 a0 = *reinterpret_cast<const half8*>(&sU[lr     ][ko]);
        const half8 a1 = *reinterpret_cast<const half8*>(&sU[16 + lr][ko]);
        #pragma unroll
        for (int nt = 0; nt < 2; ++nt) {
            const int ncol = (2*w + nt)*16 + lr;
            const half8 bT = *reinterpret_cast<const half8*>(&Tg[ncol*LC + ko]);
            const half8 bG = *reinterpret_cast<const half8*>(&Gg[ncol*LC + ko]);
            accA[0][nt] = __builtin_amdgcn_mfma_f32_16x16x32_f16(a0, bT, accA[0][nt], 0, 0, 0);
            accA[1][nt] = __builtin_amdgcn_mfma_f32_16x16x32_f16(a1, bT, accA[1][nt], 0, 0, 0);
            accB[0][nt] = __builtin_amdgcn_mfma_f32_16x16x32_f16(a0, bG, accB[0][nt], 0, 0, 0);
            accB[1][nt] = __builtin_amdgcn_mfma_f32_16x16x32_f16(a1, bG, accB[1][nt], 0, 0, 0);
        }
    }
    // spill E fragments to LDS
    #pragma unroll
    for (int mt = 0; mt < 2; ++mt)
        #pragma unroll
        for (int nt = 0; nt < 2; ++nt)
            #pragma unroll
            for (int j = 0; j < 4; ++j)
                sE[mt*16 + lg*4 + j][(2*w + nt)*16 + lr] = accB[mt][nt][j];
    __syncthreads();

    // carry scan (wave 0; lane = mode). carry_0 = 0; carry_{k+1} = q*carry_k + E_k
    if (w == 0) {
        const float qre = qg[2*l], qim = qg[2*l+1];
        float cr = 0.f, ci = 0.f;
        #pragma unroll
        for (int k = 0; k < NCH; ++k) {
            const float er = sE[k][2*l], ei = sE[k][2*l+1];
            *reinterpret_cast<f16x2*>(&sC[k][2*l]) =
                (f16x2){ (f16)(cr * 0.0625f), (f16)(ci * 0.0625f) };
            const float ncr = fmaf(qre, cr, fmaf(-qim, ci, er));
            const float nci = fmaf(qre, ci, fmaf( qim, cr, ei));
            cr = ncr; ci = nci;
        }
    }
    __syncthreads();

    // phase C: Y += C * M (chained into accA)
    #pragma unroll
    for (int ks = 0; ks < 4; ++ks) {
        const int ko = ks*32 + lg*8;
        const half8 a0 = *reinterpret_cast<const half8*>(&sC[lr     ][ko]);
        const half8 a1 = *reinterpret_cast<const half8*>(&sC[16 + lr][ko]);
        #pragma unroll
        for (int nt = 0; nt < 2; ++nt) {
            const int ncol = (2*w + nt)*16 + lr;
            const half8 bM = *reinterpret_cast<const half8*>(&Mg[ncol*LC + ko]);
            accA[0][nt] = __builtin_amdgcn_mfma_f32_16x16x32_f16(a0, bM, accA[0][nt], 0, 0, 0);
            accA[1][nt] = __builtin_amdgcn_mfma_f32_16x16x32_f16(a1, bM, accA[1][nt], 0, 0, 0);
        }
    }

    // epilogue: fragments -> LDS (sE dead after scan), then coalesced float4 out
    #pragma unroll
    for (int mt = 0; mt < 2; ++mt)
        #pragma unroll
        for (int nt = 0; nt < 2; ++nt)
            #pragma unroll
            for (int j = 0; j < 4; ++j)
                sE[mt*16 + lg*4 + j][(2*w + nt)*16 + lr] = accA[mt][nt][j];
    __syncthreads();
    {
        float4* op = reinterpret_cast<float4*>(out + (size_t)bh * L_);
        #pragma unroll
        for (int i = 0; i < L_/4/256; ++i) {
            const int e4 = t + i*256;
            const int row = e4 >> 5, c4 = (e4 & 31) * 4;
            op[e4] = *reinterpret_cast<const float4*>(&sE[row][c4]);
        }
    }
}

extern "C" void kernel_launch(void* const* d_in, const int* in_sizes, int n_in,
                              void* d_out, int out_size, void* d_ws, size_t ws_size,
                              hipStream_t stream) {
    const float* u  = (const float*)d_in[0];
    const float* lr = (const float*)d_in[1];
    const float* li = (const float*)d_in[2];
    const float* w  = (const float*)d_in[3];
    const float* dv = (const float*)d_in[4];
    const float* ls = (const float*)d_in[5];
    float* out = (float*)d_out;
    char* ws = (char*)d_ws;
    dss_prep<<<dim3(H_, 3), dim3(256), 0, stream>>>(lr, li, w, dv, ls, ws);
    dss_main<<<dim3(B_*H_), dim3(256), 0, stream>>>(u, ws, out);
}